// Round 5
// baseline (630.649 us; speedup 1.0000x reference)
//
#include <hip/hip_runtime.h>

#define EPSF 1e-7f
#define NCLS 46
#define BLOCK 256
#define GRID (23 * 88)   // 2024 blocks = 8096 waves ~ 98.8% of 8192 wave slots

// d_ws layout (floats): [0,46) col_sum | [46,92) tp | [92,138) cnt | [138] ticket
__global__ __launch_bounds__(BLOCK, 8) void f1_fused(
    const float* __restrict__ yp,    // y_pred f32 [N*46]
    const int* __restrict__ yt,      // y_true int32 [N]
    float* __restrict__ g,           // 139 floats, zeroed by memsetAsync
    float* __restrict__ out,         // f32 scalar
    int n_rows)
{
    __shared__ float s_cs[NCLS], s_tp[NCLS], s_cnt[NCLS];
    __shared__ int s_last;
    const int tid = threadIdx.x;
    for (int i = tid; i < NCLS; i += BLOCK) { s_cs[i] = 0.f; s_tp[i] = 0.f; s_cnt[i] = 0.f; }
    __syncthreads();

    const int T = BLOCK * GRID;           // multiple of 23
    const int t = blockIdx.x * BLOCK + tid;
    // Row-pair = 2 rows = 92 f32 = 23 float4 slots; thread owns slot s forever.
    const int s        = t % 23;
    const int rp0      = t / 23;
    const int rpstride = T / 23;          // 23,552? no: T/23 = 22,528
    const int npairs   = n_rows >> 1;

    int cls[4], hi[4];
    #pragma unroll
    for (int j = 0; j < 4; ++j) {
        int e  = 4 * s + j;               // 0..91 within the pair
        hi[j]  = (e >= 46) ? 1 : 0;
        cls[j] = e - 46 * hi[j];
    }

    float cs[4] = {0.f,0.f,0.f,0.f};
    float tp[4] = {0.f,0.f,0.f,0.f};

    for (int rp = rp0; rp < npairs; rp += rpstride) {
        float4 v = *(const float4*)(yp + rp * 92 + 4 * s);   // 16B coalesced
        int2 lab = *(const int2*)(yt + 2 * rp);
        float vv[4] = {v.x, v.y, v.z, v.w};
        #pragma unroll
        for (int j = 0; j < 4; ++j) {
            cs[j] += vv[j];
            int labj = hi[j] ? lab.y : lab.x;
            tp[j] += (labj == cls[j]) ? vv[j] : 0.f;
        }
        if (s == 0) {   // one lane per slot-group owns the counts for its rows
            atomicAdd(&s_cnt[lab.x], 1.0f);
            atomicAdd(&s_cnt[lab.y], 1.0f);
        }
    }

    #pragma unroll
    for (int j = 0; j < 4; ++j) {
        atomicAdd(&s_cs[cls[j]], cs[j]);
        atomicAdd(&s_tp[cls[j]], tp[j]);
    }

    // odd-N safety: unpaired last row (not hit for N=2,000,000)
    if ((n_rows & 1) && blockIdx.x == 0 && tid < NCLS) {
        int L = n_rows - 1;
        float v = yp[L * NCLS + tid];
        atomicAdd(&s_cs[tid], v);
        if (yt[L] == tid) { atomicAdd(&s_tp[tid], v); atomicAdd(&s_cnt[tid], 1.0f); }
    }

    __syncthreads();
    for (int i = tid; i < NCLS; i += BLOCK) {
        atomicAdd(&g[i],          s_cs[i]);
        atomicAdd(&g[NCLS + i],   s_tp[i]);
        atomicAdd(&g[2*NCLS + i], s_cnt[i]);
    }

    // --- last-block epilogue (threadfence ticket pattern) ---
    __threadfence();
    __syncthreads();
    if (tid == 0) {
        unsigned int ticket = atomicAdd((unsigned int*)&g[3*NCLS], 1u);
        s_last = (ticket == (unsigned int)(gridDim.x - 1)) ? 1 : 0;
    }
    __syncthreads();
    if (s_last && tid < 64) {
        __threadfence();                      // acquire side
        volatile float* vg = g;
        float f1 = 0.f;
        if (tid < NCLS) {
            float tpv = vg[NCLS + tid];
            float p = tpv / (vg[tid]          + EPSF);  // tp/(tp+fp+eps)
            float r = tpv / (vg[2*NCLS + tid] + EPSF);  // tp/(tp+fn+eps)
            float f = 2.0f * p * r / (p + r + EPSF);
            f1 = fminf(fmaxf(f, EPSF), 1.0f - EPSF);
        }
        #pragma unroll
        for (int off = 32; off > 0; off >>= 1)
            f1 += __shfl_down(f1, off);
        if (tid == 0)
            out[0] = 1.0f - f1 * (1.0f / 46.0f);
    }
}

extern "C" void kernel_launch(void* const* d_in, const int* in_sizes, int n_in,
                              void* d_out, int out_size, void* d_ws, size_t ws_size,
                              hipStream_t stream)
{
    const float* yp = (const float*)d_in[0];   // f32, N*46
    const int* yt   = (const int*)d_in[1];     // int32, N
    const int n_rows = in_sizes[1];            // N = 2,000,000

    hipMemsetAsync(d_ws, 0, (3 * NCLS + 1) * sizeof(float), stream);
    f1_fused<<<GRID, BLOCK, 0, stream>>>(yp, yt, (float*)d_ws, (float*)d_out, n_rows);
}